// Round 10
// baseline (33.987 us; speedup 1.0000x reference)
//
#include <hip/hip_runtime.h>

// Separable cubic-B-spline coefficient->value filter:
// out = F_D(F_H(F_W(coeff))), 3-tap [1/6, 4/6, 1/6], zero padding.
// Shape: (B*C=4, D=160, H=192, W=160), fp32.
//
// R10: R9's T3/T4 staging pipeline (3-slot LDS ring, counted vmcnt, raw
// s_barrier) + DENSE STORES via an LDS output tile. R9's stores were 8 B at
// 40 B lane stride -> ~40 cache-line transactions per wave store instr
// (~12 us of TA serialization chip-wide). Now: ds_write 10 floats/thread,
// barrier, then lane-contiguous f32x2 stores (512 B/instr, 8 lines).
//
// vmcnt ledger (per wave; stage = 5 gload_lds, stores = 5/iter, in-order):
//   iter i waits stage(i+1) [issued iter i-2]. Suffix after it:
//   st(i-2):5 + stage(i+2):5 + st(i-1):5 = 15  -> VMCNT(15) steady.
//   i=0: 5 (prologue queue = s(1),s(2));  i=1: 10 (no st(-1));
//   i=Zt-1: 10 (no stage issued at iter Zt-2).
// WAR: ring slot overwritten by stage(i+3) was last read at iter i-1,
// sealed by iter i's top barrier. Out-tile: reads of iter i complete
// before iter i's stores issue (reg dependency); writes of iter i+1 come
// after iter i+1's top barrier.

typedef float f32x2 __attribute__((ext_vector_type(2)));

static constexpr int Dd = 160, Hh = 192, Ww = 160, BC = 4;
static constexpr int Zt = 8, Yt = 16;
static constexpr int NZB = Dd / Zt;   // 20
static constexpr int NYB = Hh / Yt;   // 12
static constexpr float KW1 = 1.0f / 6.0f;
static constexpr float KW0 = 2.0f / 3.0f;

// Input patch row: 164 floats = 656 B = 41*16 B (one gload16 per row).
static constexpr int ROWF   = 164;
static constexpr int PROWS  = 20;            // 18 used + 2 dummy (uniform 5/wave)
static constexpr int PATCHF = PROWS * ROWF;  // 3280 floats
// Output tile: 16 rows x 160 floats, stride 164 (16B-aligned rows, bank spread).
static constexpr int OTROWF = 164;
static constexpr int OTF    = Yt * OTROWF;   // 2624 floats
// Total LDS: 3*3280 + 2624 = 12464 floats = 49,856 B (<64 KB/block).

#define VMCNT(n) asm volatile("s_waitcnt vmcnt(" #n ")" ::: "memory")
#define LGKM0()  asm volatile("s_waitcnt lgkmcnt(0)" ::: "memory")
#define BAR()    __builtin_amdgcn_s_barrier()

__device__ __forceinline__ void gload16(const float* g, float* l) {
    __builtin_amdgcn_global_load_lds(
        (const __attribute__((address_space(1))) float*)g,
        (__attribute__((address_space(3))) float*)l, 16, 0, 0);
}

struct YF { float v[12]; };   // y-filtered row at w = 10wc-1 .. 10wc+10

__global__ __launch_bounds__(256, 3) void CoeffToValue_kernel(
    const float* __restrict__ in, float* __restrict__ out)
{
    __shared__ __align__(16) float lds[3 * PATCHF + OTF];
    float* const ot = lds + 3 * PATCHF;

    const int tid  = threadIdx.x;
    const int lane = tid & 63;
    const int wave = tid >> 6;
    const int wc   = tid & 15;     // w-chunk: outputs [10wc, 10wc+10)
    const int yo   = tid >> 4;     // y-output within tile: 0..15

    const int bid = blockIdx.x;
    const int zc  = bid % NZB;
    const int yb  = (bid / NZB) % NYB;
    const int bc  = bid / (NZB * NYB);
    const int z0  = zc * Zt;
    const int y0  = yb * Yt;

    // y-tap weights; zero boundary folded into weights (clamped rows finite).
    float cyw[3];
    {
        const float wy[3] = {KW1, KW0, KW1};
#pragma unroll
        for (int dy = 0; dy < 3; ++dy) {
            const int g = y0 + yo + dy - 1;
            cyw[dy] = (g >= 0 && g < Hh) ? wy[dy] : 0.0f;
        }
    }

    const size_t plane = (size_t)Hh * Ww;
    const float* inb = in + (size_t)bc * Dd * plane;

    // per-lane global w-offset for row staging (lane 0 feeds the front pad)
    const int woff = (lane == 0) ? 0 : 4 * (lane - 1);

    // Stage slice z0+k into ring slot (k+3)%3: 5 instr/wave, 1 row each.
    auto stage = [&](int k) {
        int zs = z0 + k;
        zs = zs < 0 ? 0 : (zs >= Dd ? Dd - 1 : zs);
        const float* sp = inb + (size_t)zs * plane;
        float* slot = lds + ((k + 3) % 3) * PATCHF;
        if (lane < 41) {
#pragma unroll
            for (int r = 0; r < 5; ++r) {
                const int p  = wave + 4 * r;          // LDS row 0..19
                const int ps = p > 17 ? 17 : p;       // dummies re-read row 17
                int ys = y0 - 1 + ps;
                ys = ys < 0 ? 0 : (ys >= Hh ? Hh - 1 : ys);
                gload16(sp + (size_t)ys * Ww + woff, slot + p * ROWF);
            }
        }
    };

    // y-filter slice z0+k at (yo, wc) from LDS into registers.
    auto yfilter = [&](int k) -> YF {
        const float* base = lds + ((k + 3) % 3) * PATCHF + 10 * wc + 2;
        YF o;
#pragma unroll
        for (int q = 0; q < 12; ++q) o.v[q] = 0.0f;
#pragma unroll
        for (int dy = 0; dy < 3; ++dy) {
            const float* rp = base + (yo + dy) * ROWF;
            float v[14];
#pragma unroll
            for (int r = 0; r < 7; ++r) {
                f32x2 p2 = *reinterpret_cast<const f32x2*>(rp + 2 * r);
                v[2 * r] = p2.x; v[2 * r + 1] = p2.y;
            }
            const float c = cyw[dy];
#pragma unroll
            for (int q = 0; q < 12; ++q) o.v[q] = fmaf(c, v[q + 1], o.v[q]);
        }
        return o;
    };

    // --- prologue: slices -1,0,1 staged; yf ring primed; slice 2 issued ---
    stage(-1); stage(0); stage(1);          // 15 outstanding
    VMCNT(10); BAR();                       // stage(-1) landed (all waves)
    YF a = yfilter(-1);
    VMCNT(5); BAR();                        // stage(0) landed; slot reads done
    stage(2);                               // reuses slice -1's slot
    YF b = yfilter(0);

#pragma unroll
    for (int i = 0; i < Zt; ++i) {
        if (i == 0)           { VMCNT(5);  }
        else if (i == 1)      { VMCNT(10); }
        else if (i == Zt - 1) { VMCNT(10); }
        else                  { VMCNT(15); }
        BAR();                              // stage(i+1) resident block-wide
        if (i <= Zt - 3) stage(i + 3);      // into slice i's slot (reads sealed)
        YF n = yfilter(i + 1);

        const int z = z0 + i;
        const float czm = (z > 0)      ? KW1 : 0.0f;
        const float czp = (z < Dd - 1) ? KW1 : 0.0f;

        float t[12];
#pragma unroll
        for (int q = 0; q < 12; ++q)
            t[q] = fmaf(czm, a.v[q], fmaf(KW0, b.v[q], czp * n.v[q]));
        // w-boundary: select (not multiply) so pad garbage cannot leak
        t[0]  = (wc > 0)  ? t[0]  : 0.0f;
        t[11] = (wc < 15) ? t[11] : 0.0f;

        // w-filter -> LDS out-tile (5x b64, <=2-way banks via stride 164)
        float* otw = ot + yo * OTROWF + 10 * wc;
#pragma unroll
        for (int s = 0; s < 5; ++s) {
            f32x2 o2;
            o2.x = fmaf(KW0, t[2 * s + 1], KW1 * (t[2 * s]     + t[2 * s + 2]));
            o2.y = fmaf(KW0, t[2 * s + 2], KW1 * (t[2 * s + 1] + t[2 * s + 3]));
            *reinterpret_cast<f32x2*>(otw + 2 * s) = o2;
        }
        LGKM0(); BAR();                     // out-tile complete, visible

        // Dense store: tile is contiguous in global (y-rows adjacent).
        // 5x f32x2 per thread, lane-contiguous -> 512 B per wave instr.
        float* gtile = out + ((size_t)(bc * Dd + z) * Hh + y0) * Ww;
#pragma unroll
        for (int k = 0; k < 5; ++k) {
            const int g   = tid + 256 * k;      // f32x2 index, 0..1279
            const int row = g / 80;             // 16 rows x 80 f32x2
            const int c2  = g - row * 80;
            f32x2 v = *reinterpret_cast<const f32x2*>(ot + row * OTROWF + 2 * c2);
            *reinterpret_cast<f32x2*>(gtile + 2 * g) = v;
        }

        a = b; b = n;                       // reg-resident yf ring rotate
    }
}

extern "C" void kernel_launch(void* const* d_in, const int* in_sizes, int n_in,
                              void* d_out, int out_size, void* d_ws, size_t ws_size,
                              hipStream_t stream) {
    const float* in = (const float*)d_in[0];
    float* out = (float*)d_out;

    const int blocks = BC * NYB * NZB;   // 4*12*20 = 960
    CoeffToValue_kernel<<<blocks, 256, 0, stream>>>(in, out);
}

// Round 11
// 31.036 us; speedup vs baseline: 1.0951x; 1.0951x over previous
//
#include <hip/hip_runtime.h>

// Separable cubic-B-spline coefficient->value filter:
// out = F_D(F_H(F_W(coeff))), 3-tap [1/6, 4/6, 1/6], zero padding.
// Shape: (B*C=4, D=160, H=192, W=160), fp32.
//
// R11 = R9 pipeline (3-slot LDS ring, global_load_lds, counted vmcnt, raw
// s_barrier, direct f32x2 stores) with convergence fixes:
//  - Zt 8->10: grid = 4*12*16 = 768 = EXACTLY 3 blocks/CU (no 3-vs-4
//    imbalance), staged-slice redundancy 1.25 -> 1.2.
//  - out-tile dropped (R10 proved it neutral; saves LDS/VGPR/conflicts).
//  - T1 XCD-chunked blockIdx swizzle (768%8==0, bijective): zc/yb-adjacent
//    blocks share an XCD L2 so z/y-halo re-reads can hit L2.
//
// vmcnt ledger (per wave; stage = 5 gload_lds, stores = 5/iter, in-order;
// stage(i+3) issued at top of iter i, stores at end of iter i):
//   iter 0: queue [s1,s2] -> want s1: VMCNT(5)
//   iter 1: [s2,s3,st0] -> want s2: VMCNT(10)
//   iter 2..8: [s(i+1),st(i-2),s(i+2),st(i-1)] -> VMCNT(15)
//   iter 9: [s10,st7,st8] -> want s10: VMCNT(10)
// WAR: ring slot overwritten by stage(i+3) was last read at iter i-1,
// sealed by iter i's top barrier.

typedef float f32x2 __attribute__((ext_vector_type(2)));

static constexpr int Dd = 160, Hh = 192, Ww = 160, BC = 4;
static constexpr int Zt = 10, Yt = 16;
static constexpr int NZB = Dd / Zt;   // 16
static constexpr int NYB = Hh / Yt;   // 12
static constexpr float KW1 = 1.0f / 6.0f;
static constexpr float KW0 = 2.0f / 3.0f;

// Input patch row: 164 floats = 656 B = 41*16 B (one gload16 per row;
// lane 0 fills the 4-float front pad with w=0..3, lanes 1..40 fill w=0..159).
static constexpr int ROWF   = 164;
static constexpr int PROWS  = 20;            // 18 used + 2 dummy (uniform 5/wave)
static constexpr int PATCHF = PROWS * ROWF;  // 3280 floats; 3 slots = 39,360 B

#define VMCNT(n) asm volatile("s_waitcnt vmcnt(" #n ")" ::: "memory")
#define BAR()    __builtin_amdgcn_s_barrier()

__device__ __forceinline__ void gload16(const float* g, float* l) {
    __builtin_amdgcn_global_load_lds(
        (const __attribute__((address_space(1))) float*)g,
        (__attribute__((address_space(3))) float*)l, 16, 0, 0);
}

struct YF { float v[12]; };   // y-filtered row at w = 10wc-1 .. 10wc+10

__global__ __launch_bounds__(256, 4) void CoeffToValue_kernel(
    const float* __restrict__ in, float* __restrict__ out)
{
    __shared__ __align__(16) float lds[3 * PATCHF];

    const int tid  = threadIdx.x;
    const int lane = tid & 63;
    const int wave = tid >> 6;
    const int wc   = tid & 15;     // w-chunk: outputs [10wc, 10wc+10)
    const int yo   = tid >> 4;     // y-output within tile: 0..15

    // T1: bijective XCD-chunked swizzle (768 blocks, 8 XCDs, 96/XCD).
    // Launched id round-robins XCDs by (id % 8); logical ids become
    // contiguous per XCD -> zc/yb-neighbors share an XCD L2.
    const int bid = ((blockIdx.x & 7) * 96) + (blockIdx.x >> 3);
    const int zc  = bid % NZB;
    const int yb  = (bid / NZB) % NYB;
    const int bc  = bid / (NZB * NYB);
    const int z0  = zc * Zt;
    const int y0  = yb * Yt;

    // y-tap weights; zero boundary folded into weights (clamped rows finite).
    float cyw[3];
    {
        const float wy[3] = {KW1, KW0, KW1};
#pragma unroll
        for (int dy = 0; dy < 3; ++dy) {
            const int g = y0 + yo + dy - 1;
            cyw[dy] = (g >= 0 && g < Hh) ? wy[dy] : 0.0f;
        }
    }

    const size_t plane = (size_t)Hh * Ww;
    const float* inb = in + (size_t)bc * Dd * plane;

    // per-lane global w-offset for row staging (lane 0 feeds the front pad)
    const int woff = (lane == 0) ? 0 : 4 * (lane - 1);

    // Stage slice z0+k into ring slot (k+3)%3: 5 instr/wave, 1 row each.
    auto stage = [&](int k) {
        int zs = z0 + k;
        zs = zs < 0 ? 0 : (zs >= Dd ? Dd - 1 : zs);
        const float* sp = inb + (size_t)zs * plane;
        float* slot = lds + ((k + 3) % 3) * PATCHF;
        if (lane < 41) {
#pragma unroll
            for (int r = 0; r < 5; ++r) {
                const int p  = wave + 4 * r;          // LDS row 0..19
                const int ps = p > 17 ? 17 : p;       // dummies re-read row 17
                int ys = y0 - 1 + ps;
                ys = ys < 0 ? 0 : (ys >= Hh ? Hh - 1 : ys);
                gload16(sp + (size_t)ys * Ww + woff, slot + p * ROWF);
            }
        }
    };

    // y-filter slice z0+k at (yo, wc) from LDS into registers.
    auto yfilter = [&](int k) -> YF {
        const float* base = lds + ((k + 3) % 3) * PATCHF + 10 * wc + 2;
        YF o;
#pragma unroll
        for (int q = 0; q < 12; ++q) o.v[q] = 0.0f;
#pragma unroll
        for (int dy = 0; dy < 3; ++dy) {
            const float* rp = base + (yo + dy) * ROWF;
            float v[14];
#pragma unroll
            for (int r = 0; r < 7; ++r) {
                f32x2 p2 = *reinterpret_cast<const f32x2*>(rp + 2 * r);
                v[2 * r] = p2.x; v[2 * r + 1] = p2.y;
            }
            const float c = cyw[dy];
#pragma unroll
            for (int q = 0; q < 12; ++q) o.v[q] = fmaf(c, v[q + 1], o.v[q]);
        }
        return o;
    };

    // --- prologue: slices -1,0,1 staged; yf ring primed; slice 2 issued ---
    stage(-1); stage(0); stage(1);          // 15 outstanding
    VMCNT(10); BAR();                       // stage(-1) landed (all waves)
    YF a = yfilter(-1);
    VMCNT(5); BAR();                        // stage(0) landed; slot reads done
    stage(2);                               // reuses slice -1's slot
    YF b = yfilter(0);

#pragma unroll
    for (int i = 0; i < Zt; ++i) {
        if (i == 0)           { VMCNT(5);  }
        else if (i == 1)      { VMCNT(10); }
        else if (i == Zt - 1) { VMCNT(10); }
        else                  { VMCNT(15); }
        BAR();                              // stage(i+1) resident block-wide
        if (i <= Zt - 3) stage(i + 3);      // into slice i's slot (reads sealed)
        YF n = yfilter(i + 1);

        const int z = z0 + i;
        const float czm = (z > 0)      ? KW1 : 0.0f;
        const float czp = (z < Dd - 1) ? KW1 : 0.0f;

        float t[12];
#pragma unroll
        for (int q = 0; q < 12; ++q)
            t[q] = fmaf(czm, a.v[q], fmaf(KW0, b.v[q], czp * n.v[q]));
        // w-boundary: select (not multiply) so pad garbage cannot leak
        t[0]  = (wc > 0)  ? t[0]  : 0.0f;
        t[11] = (wc < 15) ? t[11] : 0.0f;

        float* orow = out + ((size_t)(bc * Dd + z) * Hh + (y0 + yo)) * Ww + 10 * wc;
#pragma unroll
        for (int s = 0; s < 5; ++s) {
            f32x2 o2;
            o2.x = fmaf(KW0, t[2 * s + 1], KW1 * (t[2 * s]     + t[2 * s + 2]));
            o2.y = fmaf(KW0, t[2 * s + 2], KW1 * (t[2 * s + 1] + t[2 * s + 3]));
            *reinterpret_cast<f32x2*>(orow + 2 * s) = o2;
        }

        a = b; b = n;                       // reg-resident yf ring rotate
    }
}

extern "C" void kernel_launch(void* const* d_in, const int* in_sizes, int n_in,
                              void* d_out, int out_size, void* d_ws, size_t ws_size,
                              hipStream_t stream) {
    const float* in = (const float*)d_in[0];
    float* out = (float*)d_out;

    const int blocks = BC * NYB * NZB;   // 4*12*16 = 768 = exactly 3/CU
    CoeffToValue_kernel<<<blocks, 256, 0, stream>>>(in, out);
}